// Round 1
// baseline (2119.360 us; speedup 1.0000x reference)
//
#include <hip/hip_runtime.h>
#include <hip/hip_bf16.h>

// ============================================================================
// EnhancedMathematicalReasoning: B=4, S=2048, H=2048, E=8  (all fp32 I/O)
//   G1   = gelu(X @ Wd1 + bd1)                      [8192,2048]
//   opw  = softmax(G1 @ Wd2 + bd2)                  [8192,8]
//   C    = sum_e opw[:,e] * (X @ We[e] + be[e])     [8192,2048]
//   T    = gelu(C @ Wi1 + bi1)                      [8192,2048]
//   out  = (T @ Wi2 + bi2) * mask[:,None]           [8192,2048]
//
// Strategy: no fp32 MFMA on CDNA4 -> fp32 emulated as bf16 hi/lo split,
// 3 MFMA passes (hh, hl, lh), fp32 accumulate. Error ~1e-5 (vs bf16-single
// ~3e-2). All big GEMMs: 128x128 tile, BK=64, 4 waves, global_load_lds(16B),
// XOR-swizzled LDS (slot ^= row&7) with pre-swizzled global source.
// ============================================================================

#define MTOT 8192
#define HDIM 2048

typedef short bf16x8 __attribute__((ext_vector_type(8)));
typedef float f32x4  __attribute__((ext_vector_type(4)));

__device__ __forceinline__ unsigned short f2bf(float x) {
    unsigned int u = __float_as_uint(x);
    unsigned int r = (u + 0x7FFFu + ((u >> 16) & 1u)) >> 16;   // RNE
    return (unsigned short)r;
}
__device__ __forceinline__ float bf2f(unsigned short u) {
    return __uint_as_float(((unsigned int)u) << 16);
}
__device__ __forceinline__ float gelu_f(float x) {
    return 0.5f * x * (1.0f + erff(x * 0.70710678118654752f));
}

// ---------------------------------------------------------------------------
// Split X (fp32, row-major [M][2048]) into hi/lo bf16 (same layout).
// ---------------------------------------------------------------------------
__global__ void k_split_x(const float* __restrict__ x,
                          unsigned short* __restrict__ hi,
                          unsigned short* __restrict__ lo, long n) {
    long i = ((long)blockIdx.x * blockDim.x + threadIdx.x) * 4;
    long stride = (long)gridDim.x * blockDim.x * 4;
    for (; i < n; i += stride) {
        float4 v = *reinterpret_cast<const float4*>(x + i);
        ushort4 h, l;
        h.x = f2bf(v.x); l.x = f2bf(v.x - bf2f(h.x));
        h.y = f2bf(v.y); l.y = f2bf(v.y - bf2f(h.y));
        h.z = f2bf(v.z); l.z = f2bf(v.z - bf2f(h.z));
        h.w = f2bf(v.w); l.w = f2bf(v.w - bf2f(h.w));
        *reinterpret_cast<ushort4*>(hi + i) = h;
        *reinterpret_cast<ushort4*>(lo + i) = l;
    }
}

// ---------------------------------------------------------------------------
// Split + transpose the 11 [K=2048][N=2048] weight mats into [N][K] hi/lo bf16.
// z: 0 -> Wd1, 1..8 -> We[z-1], 9 -> Wi1, 10 -> Wi2.
// ---------------------------------------------------------------------------
__global__ void k_split_tr(const float* __restrict__ Wd1, const float* __restrict__ We,
                           const float* __restrict__ Wi1, const float* __restrict__ Wi2,
                           unsigned short* __restrict__ th, unsigned short* __restrict__ tl) {
    int z = blockIdx.z;
    const float* src = (z == 0) ? Wd1
                     : (z <= 8) ? (We + (size_t)(z - 1) * HDIM * HDIM)
                     : (z == 9) ? Wi1 : Wi2;
    size_t dof = (size_t)z * HDIM * HDIM;
    __shared__ float t[32][33];
    int n0 = blockIdx.x * 32, k0 = blockIdx.y * 32;
    int tx = threadIdx.x & 31, ty = threadIdx.x >> 5;   // ty in [0,8)
#pragma unroll
    for (int i = 0; i < 4; ++i) {
        int k = ty + i * 8;
        t[k][tx] = src[(size_t)(k0 + k) * HDIM + n0 + tx];
    }
    __syncthreads();
#pragma unroll
    for (int i = 0; i < 4; ++i) {
        int n = ty + i * 8;
        float v = t[tx][n];                     // = src[k0+tx][n0+n]
        unsigned short hv = f2bf(v);
        unsigned short lv = f2bf(v - bf2f(hv));
        th[dof + (size_t)(n0 + n) * HDIM + k0 + tx] = hv;
        tl[dof + (size_t)(n0 + n) * HDIM + k0 + tx] = lv;
    }
}

// ---------------------------------------------------------------------------
// Router: logits = G1 @ Wd2 + bd2 (fp32 vector), softmax -> opw [M][8].
// One wave per row.
// ---------------------------------------------------------------------------
__global__ void k_logits(const float* __restrict__ G1, const float* __restrict__ Wd2,
                         const float* __restrict__ bd2, float* __restrict__ opw) {
    int row = blockIdx.x * (blockDim.x >> 6) + (threadIdx.x >> 6);
    int lane = threadIdx.x & 63;
    if (row >= MTOT) return;
    const float* g = G1 + (size_t)row * HDIM;
    float a[8] = {0, 0, 0, 0, 0, 0, 0, 0};
    for (int k = lane; k < HDIM; k += 64) {
        float x = g[k];
        const float* w = Wd2 + (size_t)k * 8;
        float4 w0 = *reinterpret_cast<const float4*>(w);
        float4 w1 = *reinterpret_cast<const float4*>(w + 4);
        a[0] += x * w0.x; a[1] += x * w0.y; a[2] += x * w0.z; a[3] += x * w0.w;
        a[4] += x * w1.x; a[5] += x * w1.y; a[6] += x * w1.z; a[7] += x * w1.w;
    }
#pragma unroll
    for (int off = 32; off > 0; off >>= 1)
#pragma unroll
        for (int e = 0; e < 8; ++e) a[e] += __shfl_xor(a[e], off);
#pragma unroll
    for (int e = 0; e < 8; ++e) a[e] += bd2[e];
    float mx = a[0];
#pragma unroll
    for (int e = 1; e < 8; ++e) mx = fmaxf(mx, a[e]);
    float p[8], s = 0.f;
#pragma unroll
    for (int e = 0; e < 8; ++e) { p[e] = expf(a[e] - mx); s += p[e]; }
    float inv = 1.f / s;
    if (lane < 8) opw[(size_t)row * 8 + lane] = p[lane] * inv;
}

// ---------------------------------------------------------------------------
// GEMM machinery: 128x128 tile, BK=64. LDS: 4 tiles [128][64] bf16 (Ah Al Bh Bl)
// = 64KB. XOR swizzle on the 16B slot index: slot ^= (row & 7).
// global_load_lds writes LDS linearly -> pre-swizzle the GLOBAL source chunk.
// ---------------------------------------------------------------------------
__device__ __forceinline__ void stage_tile(const unsigned short* __restrict__ g,
                                           unsigned short* l, int row0, int kt, int tid) {
    int wv = tid >> 6;
#pragma unroll
    for (int i = 0; i < 4; ++i) {
        int idx = i * 256 + tid;            // linear 16B-slot index in tile
        int row = idx >> 3;
        int chunk = (idx & 7) ^ (row & 7);  // swizzled source chunk
        const unsigned short* src = g + ((size_t)(row0 + row) << 11) + kt + (chunk << 3);
        unsigned short* dst = l + (size_t)((i * 256 + wv * 64) << 3);  // wave-uniform
        __builtin_amdgcn_global_load_lds((const __attribute__((address_space(1))) void*)src,
                                         (__attribute__((address_space(3))) void*)dst,
                                         16, 0, 0);
    }
}

__device__ __forceinline__ bf16x8 rd_frag(const unsigned short* l, int r, int kslot) {
    int slot = kslot ^ (r & 7);
    return *reinterpret_cast<const bf16x8*>(l + r * 64 + slot * 8);
}

#define MFMA3(ACC, AH, AL, BH, BL)                                              \
    ACC = __builtin_amdgcn_mfma_f32_16x16x32_bf16(AH, BH, ACC, 0, 0, 0);        \
    ACC = __builtin_amdgcn_mfma_f32_16x16x32_bf16(AH, BL, ACC, 0, 0, 0);        \
    ACC = __builtin_amdgcn_mfma_f32_16x16x32_bf16(AL, BH, ACC, 0, 0, 0);

// EPI: 0 = +bias, gelu, fp32 out (G1)
//      2 = +bias, gelu, split hi/lo out (T)
//      3 = +bias, *mask[row], fp32 out (final)
template <int EPI>
__global__ __launch_bounds__(256, 2)
void k_gemm(const unsigned short* __restrict__ Ah, const unsigned short* __restrict__ Al,
            const unsigned short* __restrict__ Bh, const unsigned short* __restrict__ Bl,
            const float* __restrict__ bias, const float* __restrict__ mask,
            float* __restrict__ outF,
            unsigned short* __restrict__ oHi, unsigned short* __restrict__ oLo) {
    __shared__ unsigned short lds[4 * 8192];
    const int tid = threadIdx.x, lane = tid & 63, wv = tid >> 6;
    const int row0 = blockIdx.y * 128, col0 = blockIdx.x * 128;
    const int wm = wv >> 1, wn = wv & 1;
    f32x4 acc[4][4] = {};

    for (int kt = 0; kt < HDIM; kt += 64) {
        stage_tile(Ah, lds,          row0, kt, tid);
        stage_tile(Al, lds + 8192,   row0, kt, tid);
        stage_tile(Bh, lds + 16384,  col0, kt, tid);
        stage_tile(Bl, lds + 24576,  col0, kt, tid);
        __syncthreads();
#pragma unroll
        for (int kk = 0; kk < 2; ++kk) {
            const int ks = (kk << 2) + (lane >> 4);
            bf16x8 fah[4], fal[4], fbh[4], fbl[4];
#pragma unroll
            for (int m = 0; m < 4; ++m) {
                int r = wm * 64 + m * 16 + (lane & 15);
                fah[m] = rd_frag(lds, r, ks);
                fal[m] = rd_frag(lds + 8192, r, ks);
            }
#pragma unroll
            for (int n = 0; n < 4; ++n) {
                int c = wn * 64 + n * 16 + (lane & 15);
                fbh[n] = rd_frag(lds + 16384, c, ks);
                fbl[n] = rd_frag(lds + 24576, c, ks);
            }
#pragma unroll
            for (int m = 0; m < 4; ++m)
#pragma unroll
                for (int n = 0; n < 4; ++n) {
                    MFMA3(acc[m][n], fah[m], fal[m], fbh[n], fbl[n]);
                }
        }
        __syncthreads();
    }

#pragma unroll
    for (int m = 0; m < 4; ++m)
#pragma unroll
        for (int n = 0; n < 4; ++n) {
            int gc = col0 + wn * 64 + n * 16 + (lane & 15);
            float bv = bias[gc];
#pragma unroll
            for (int r = 0; r < 4; ++r) {
                int gr = row0 + wm * 64 + m * 16 + ((lane >> 4) << 2) + r;
                float v = acc[m][n][r] + bv;
                if constexpr (EPI == 0) {
                    outF[(size_t)gr * HDIM + gc] = gelu_f(v);
                } else if constexpr (EPI == 2) {
                    v = gelu_f(v);
                    unsigned short hv = f2bf(v), lv = f2bf(v - bf2f(hv));
                    oHi[(size_t)gr * HDIM + gc] = hv;
                    oLo[(size_t)gr * HDIM + gc] = lv;
                } else {
                    outF[(size_t)gr * HDIM + gc] = v * mask[gr];
                }
            }
        }
}

// ---------------------------------------------------------------------------
// Fused expert GEMMs: C = sum_e opw[:,e] * (X @ WeT[e] + be[e]), split hi/lo.
// ---------------------------------------------------------------------------
__global__ __launch_bounds__(256, 2)
void k_experts(const unsigned short* __restrict__ Xh, const unsigned short* __restrict__ Xl,
               const unsigned short* __restrict__ Wh, const unsigned short* __restrict__ Wl,
               const float* __restrict__ be, const float* __restrict__ opw,
               unsigned short* __restrict__ oHi, unsigned short* __restrict__ oLo) {
    __shared__ unsigned short lds[4 * 8192];
    const int tid = threadIdx.x, lane = tid & 63, wv = tid >> 6;
    const int row0 = blockIdx.y * 128, col0 = blockIdx.x * 128;
    const int wm = wv >> 1, wn = wv & 1;
    f32x4 accc[4][4] = {};

    for (int e = 0; e < 8; ++e) {
        const unsigned short* Bh = Wh + (size_t)e * HDIM * HDIM;
        const unsigned short* Bl = Wl + (size_t)e * HDIM * HDIM;
        f32x4 acc[4][4] = {};
        for (int kt = 0; kt < HDIM; kt += 64) {
            stage_tile(Xh, lds,          row0, kt, tid);
            stage_tile(Xl, lds + 8192,   row0, kt, tid);
            stage_tile(Bh, lds + 16384,  col0, kt, tid);
            stage_tile(Bl, lds + 24576,  col0, kt, tid);
            __syncthreads();
#pragma unroll
            for (int kk = 0; kk < 2; ++kk) {
                const int ks = (kk << 2) + (lane >> 4);
                bf16x8 fah[4], fal[4], fbh[4], fbl[4];
#pragma unroll
                for (int m = 0; m < 4; ++m) {
                    int r = wm * 64 + m * 16 + (lane & 15);
                    fah[m] = rd_frag(lds, r, ks);
                    fal[m] = rd_frag(lds + 8192, r, ks);
                }
#pragma unroll
                for (int n = 0; n < 4; ++n) {
                    int c = wn * 64 + n * 16 + (lane & 15);
                    fbh[n] = rd_frag(lds + 16384, c, ks);
                    fbl[n] = rd_frag(lds + 24576, c, ks);
                }
#pragma unroll
                for (int m = 0; m < 4; ++m)
#pragma unroll
                    for (int n = 0; n < 4; ++n) {
                        MFMA3(acc[m][n], fah[m], fal[m], fbh[n], fbl[n]);
                    }
            }
            __syncthreads();
        }
        // weighted accumulate into combined
#pragma unroll
        for (int m = 0; m < 4; ++m)
#pragma unroll
            for (int r = 0; r < 4; ++r) {
                int gr = row0 + wm * 64 + m * 16 + ((lane >> 4) << 2) + r;
                float w = opw[(size_t)gr * 8 + e];
#pragma unroll
                for (int n = 0; n < 4; ++n) {
                    int gc = col0 + wn * 64 + n * 16 + (lane & 15);
                    accc[m][n][r] += w * (acc[m][n][r] + be[e * HDIM + gc]);
                }
            }
    }

#pragma unroll
    for (int m = 0; m < 4; ++m)
#pragma unroll
        for (int n = 0; n < 4; ++n) {
            int gc = col0 + wn * 64 + n * 16 + (lane & 15);
#pragma unroll
            for (int r = 0; r < 4; ++r) {
                int gr = row0 + wm * 64 + m * 16 + ((lane >> 4) << 2) + r;
                float v = accc[m][n][r];
                unsigned short hv = f2bf(v), lv = f2bf(v - bf2f(hv));
                oHi[(size_t)gr * HDIM + gc] = hv;
                oLo[(size_t)gr * HDIM + gc] = lv;
            }
        }
}

// ---------------------------------------------------------------------------
extern "C" void kernel_launch(void* const* d_in, const int* in_sizes, int n_in,
                              void* d_out, int out_size, void* d_ws, size_t ws_size,
                              hipStream_t stream) {
    const float* h    = (const float*)d_in[0];
    const float* amsk = (const float*)d_in[1];
    const float* Wd1  = (const float*)d_in[2];
    const float* bd1  = (const float*)d_in[3];
    const float* Wd2  = (const float*)d_in[4];
    const float* bd2  = (const float*)d_in[5];
    const float* We   = (const float*)d_in[6];
    const float* be   = (const float*)d_in[7];
    const float* Wi1  = (const float*)d_in[8];
    const float* bi1  = (const float*)d_in[9];
    const float* Wi2  = (const float*)d_in[10];
    const float* bi2  = (const float*)d_in[11];
    float* out = (float*)d_out;

    const size_t MB = 1ull << 20;
    char* ws = (char*)d_ws;
    // Region A [0,64MB): Xhi/Xlo, later reused for Thi/Tlo.
    unsigned short* Xh = (unsigned short*)(ws);
    unsigned short* Xl = (unsigned short*)(ws + 32 * MB);
    // Region B [64MB,240MB): 11 transposed weight mats, hi then lo (88MB each).
    unsigned short* Wth = (unsigned short*)(ws + 64 * MB);
    unsigned short* Wtl = (unsigned short*)(ws + 152 * MB);
    // Region C [240MB,304MB): G1 fp32, later reused for Chi/Clo.
    char* rc = ws + 240 * MB;
    float*          G1  = (float*)rc;
    unsigned short* Chi = (unsigned short*)rc;
    unsigned short* Clo = (unsigned short*)(rc + 32 * MB);
    // Region D: opw (256KB).
    float* opw = (float*)(ws + 304 * MB);
    unsigned short* Thi = Xh;
    unsigned short* Tlo = Xl;

    const size_t WMAT = (size_t)HDIM * HDIM;  // elements per matrix
    dim3 gemm_grid(HDIM / 128, MTOT / 128);   // (16, 64)

    // 1. split X -> hi/lo bf16
    k_split_x<<<4096, 256, 0, stream>>>(h, Xh, Xl, (long)MTOT * HDIM);
    // 2. split + transpose 11 weight matrices
    k_split_tr<<<dim3(64, 64, 11), 256, 0, stream>>>(Wd1, We, Wi1, Wi2, Wth, Wtl);
    // 3. G1 = gelu(X @ Wd1 + bd1)
    k_gemm<0><<<gemm_grid, 256, 0, stream>>>(Xh, Xl, Wth, Wtl, bd1, nullptr,
                                             G1, nullptr, nullptr);
    // 4. opw = softmax(G1 @ Wd2 + bd2)
    k_logits<<<MTOT / 4, 256, 0, stream>>>(G1, Wd2, bd2, opw);
    // 5. C = sum_e opw .* (X @ We[e]^T + be[e])  -> hi/lo
    k_experts<<<gemm_grid, 256, 0, stream>>>(Xh, Xl, Wth + WMAT, Wtl + WMAT,
                                             be, opw, Chi, Clo);
    // 6. T = gelu(C @ Wi1 + bi1) -> hi/lo
    k_gemm<2><<<gemm_grid, 256, 0, stream>>>(Chi, Clo, Wth + 9 * WMAT, Wtl + 9 * WMAT,
                                             bi1, nullptr, nullptr, Thi, Tlo);
    // 7. out = (T @ Wi2 + bi2) * mask
    k_gemm<3><<<gemm_grid, 256, 0, stream>>>(Thi, Tlo, Wth + 10 * WMAT, Wtl + 10 * WMAT,
                                             bi2, amsk, out, nullptr, nullptr);
}